// Round 2
// baseline (1981.979 us; speedup 1.0000x reference)
//
#include <hip/hip_runtime.h>
#include <hip/hip_bf16.h>

#define N_NODES 100000
#define N_EDGES 3200000
#define C_OUT 64
#define C_HID 128
#define C_IN 512

// ---------------- degree histogram ----------------
__global__ __launch_bounds__(256) void hist_kernel(const int* __restrict__ cols,
                                                   int* __restrict__ cnt) {
    int e = blockIdx.x * 256 + threadIdx.x;
    if (e < N_EDGES) atomicAdd(&cnt[cols[e]], 1);
}

__global__ __launch_bounds__(256) void dis_kernel(const int* __restrict__ cnt,
                                                  float* __restrict__ dis) {
    int i = blockIdx.x * 256 + threadIdx.x;
    if (i < N_NODES) dis[i] = rsqrtf((float)(cnt[i] + 1));  // +1 self loop
}

// ---------------- exclusive scan (3 kernels) ----------------
__global__ __launch_bounds__(256) void scanA(const int* __restrict__ cnt,
                                             int* __restrict__ offs,
                                             int* __restrict__ bsum, int n) {
    __shared__ int sh[256];
    int b = blockIdx.x, tid = threadIdx.x;
    int base = b * 1024;
    int v[4]; int s = 0;
#pragma unroll
    for (int i = 0; i < 4; i++) {
        int idx = base + tid * 4 + i;
        v[i] = (idx < n) ? cnt[idx] : 0;
        s += v[i];
    }
    sh[tid] = s;
    __syncthreads();
    for (int st = 1; st < 256; st <<= 1) {
        int a = (tid >= st) ? sh[tid - st] : 0;
        int t = sh[tid];
        __syncthreads();
        sh[tid] = t + a;
        __syncthreads();
    }
    int run = sh[tid] - s;  // exclusive prefix of this thread's chunk
#pragma unroll
    for (int i = 0; i < 4; i++) {
        int idx = base + tid * 4 + i;
        run += v[i];
        if (idx < n) offs[idx + 1] = run;  // inclusive within block
    }
    if (tid == 255) bsum[b] = sh[255];
}

__global__ __launch_bounds__(256) void scanB(int* __restrict__ bsum, int nb) {
    __shared__ int sh[256];
    int tid = threadIdx.x;
    int v = (tid < nb) ? bsum[tid] : 0;
    sh[tid] = v;
    __syncthreads();
    for (int st = 1; st < 256; st <<= 1) {
        int a = (tid >= st) ? sh[tid - st] : 0;
        int t = sh[tid];
        __syncthreads();
        sh[tid] = t + a;
        __syncthreads();
    }
    if (tid < nb) bsum[tid] = sh[tid] - v;  // exclusive
}

__global__ __launch_bounds__(256) void scanC(int* __restrict__ offs,
                                             const int* __restrict__ bsum, int n) {
    int idx = blockIdx.x * 256 + threadIdx.x;
    if (idx < n) offs[idx + 1] += bsum[idx >> 10];
    if (idx == 0) offs[0] = 0;
}

// ---------------- CSC fill ----------------
__global__ __launch_bounds__(256) void fill_kernel(const int* __restrict__ rows,
                                                   const int* __restrict__ cols,
                                                   const float* __restrict__ dis,
                                                   const int* __restrict__ offs,
                                                   int* __restrict__ cursor,
                                                   int* __restrict__ csr_row,
                                                   float* __restrict__ csr_norm) {
    int e = blockIdx.x * 256 + threadIdx.x;
    if (e >= N_EDGES) return;
    int r = rows[e], c = cols[e];
    float w = dis[r] * dis[c];
    int p = atomicAdd(&cursor[c], 1);
    int idx = offs[c] + p;
    csr_row[idx] = r;
    csr_norm[idx] = w;
}

// ---------------- GEMM1: h1 = relu(x @ W1 + b1), [N,128] ----------------
__global__ __launch_bounds__(256) void gemm1(const float* __restrict__ X,
                                             const float* __restrict__ W1,
                                             const float* __restrict__ B1,
                                             float* __restrict__ H1) {
    __shared__ float xs[64][36];   // 64 rows x 32 k (+4 pad)
    __shared__ float ws[32][128];  // 32 k x 128 cols
    int tid = threadIdx.x;
    int tx = tid & 15, ty = tid >> 4;
    int row0 = blockIdx.x * 64;
    float acc[4][8];
#pragma unroll
    for (int i = 0; i < 4; i++)
#pragma unroll
        for (int j = 0; j < 8; j++) acc[i][j] = 0.f;

    for (int kb = 0; kb < C_IN; kb += 32) {
#pragma unroll
        for (int l = 0; l < 2; l++) {
            int idx = tid + l * 256;  // 0..511
            int r = idx >> 3;
            int k4 = idx & 7;
            int gr = row0 + r;
            float4 v = {0, 0, 0, 0};
            if (gr < N_NODES)
                v = *reinterpret_cast<const float4*>(X + (size_t)gr * C_IN + kb + k4 * 4);
            xs[r][k4 * 4 + 0] = v.x;
            xs[r][k4 * 4 + 1] = v.y;
            xs[r][k4 * 4 + 2] = v.z;
            xs[r][k4 * 4 + 3] = v.w;
        }
#pragma unroll
        for (int l = 0; l < 4; l++) {
            int idx = tid + l * 256;  // 0..1023
            int k = idx >> 5;
            int c4 = idx & 31;
            *reinterpret_cast<float4*>(&ws[k][c4 * 4]) =
                *reinterpret_cast<const float4*>(W1 + (size_t)(kb + k) * C_HID + c4 * 4);
        }
        __syncthreads();
#pragma unroll
        for (int k = 0; k < 32; k++) {
            float xv[4], wv[8];
#pragma unroll
            for (int i = 0; i < 4; i++) xv[i] = xs[ty * 4 + i][k];
#pragma unroll
            for (int j = 0; j < 8; j++) wv[j] = ws[k][tx * 8 + j];
#pragma unroll
            for (int i = 0; i < 4; i++)
#pragma unroll
                for (int j = 0; j < 8; j++) acc[i][j] += xv[i] * wv[j];
        }
        __syncthreads();
    }
#pragma unroll
    for (int i = 0; i < 4; i++) {
        int gr = row0 + ty * 4 + i;
        if (gr < N_NODES) {
#pragma unroll
            for (int j = 0; j < 8; j++) {
                int c = tx * 8 + j;
                float v = acc[i][j] + B1[c];
                H1[(size_t)gr * C_HID + c] = v > 0.f ? v : 0.f;
            }
        }
    }
}

// ---------------- GEMM2: h = h1 @ W2 + b2, [N,64] ----------------
__global__ __launch_bounds__(256) void gemm2(const float* __restrict__ H1,
                                             const float* __restrict__ W2,
                                             const float* __restrict__ B2,
                                             float* __restrict__ H) {
    __shared__ float hs[64][132];  // 64 rows x 128 k (+4 pad)
    __shared__ float ws[128][64];  // 128 k x 64 cols
    int tid = threadIdx.x;
    int tx = tid & 15, ty = tid >> 4;
    int row0 = blockIdx.x * 64;
#pragma unroll
    for (int l = 0; l < 8; l++) {
        int idx = tid + l * 256;  // 0..2047
        int k = idx >> 4;
        int c4 = idx & 15;
        *reinterpret_cast<float4*>(&ws[k][c4 * 4]) =
            *reinterpret_cast<const float4*>(W2 + (size_t)k * C_OUT + c4 * 4);
    }
#pragma unroll
    for (int l = 0; l < 8; l++) {
        int idx = tid + l * 256;  // 0..2047
        int r = idx >> 5;
        int k4 = idx & 31;
        int gr = row0 + r;
        float4 v = {0, 0, 0, 0};
        if (gr < N_NODES)
            v = *reinterpret_cast<const float4*>(H1 + (size_t)gr * C_HID + k4 * 4);
        hs[r][k4 * 4 + 0] = v.x;
        hs[r][k4 * 4 + 1] = v.y;
        hs[r][k4 * 4 + 2] = v.z;
        hs[r][k4 * 4 + 3] = v.w;
    }
    __syncthreads();
    float acc[4][4];
#pragma unroll
    for (int i = 0; i < 4; i++)
#pragma unroll
        for (int j = 0; j < 4; j++) acc[i][j] = 0.f;
#pragma unroll 4
    for (int k = 0; k < C_HID; k++) {
        float hv[4], wv[4];
#pragma unroll
        for (int i = 0; i < 4; i++) hv[i] = hs[ty * 4 + i][k];
#pragma unroll
        for (int j = 0; j < 4; j++) wv[j] = ws[k][tx * 4 + j];
#pragma unroll
        for (int i = 0; i < 4; i++)
#pragma unroll
            for (int j = 0; j < 4; j++) acc[i][j] += hv[i] * wv[j];
    }
#pragma unroll
    for (int i = 0; i < 4; i++) {
        int gr = row0 + ty * 4 + i;
        if (gr < N_NODES) {
#pragma unroll
            for (int j = 0; j < 4; j++) {
                int c = tx * 4 + j;
                H[(size_t)gr * C_OUT + c] = acc[i][j] + B2[c];
            }
        }
    }
}

// ---------------- APPNP propagate step ----------------
// one wave per node; 4 edge-groups x 16 lanes; each lane handles 4 channels (float4)
__global__ __launch_bounds__(256) void prop_kernel(const float* __restrict__ src,
                                                   const float* __restrict__ hsrc,
                                                   float* __restrict__ dst,
                                                   const int* __restrict__ offs,
                                                   const int* __restrict__ csr_row,
                                                   const float* __restrict__ csr_norm,
                                                   const float* __restrict__ dis) {
    int wid = (blockIdx.x * 256 + threadIdx.x) >> 6;
    if (wid >= N_NODES) return;
    int lane = threadIdx.x & 63;
    int g = lane >> 4;    // edge group 0..3
    int cq = lane & 15;   // channel quad: channels cq*4..cq*4+3
    int beg = offs[wid], end = offs[wid + 1];
    float ax = 0.f, ay = 0.f, az = 0.f, aw = 0.f;
    for (int j = beg; j < end; j += 4) {
        int jj = j + g;
        int r = 0;
        float w = 0.f;
        if (jj < end) {
            r = csr_row[jj];
            w = csr_norm[jj];
        }
        const float4 v =
            *reinterpret_cast<const float4*>(src + ((size_t)r << 6) + (cq << 2));
        ax += w * v.x;
        ay += w * v.y;
        az += w * v.z;
        aw += w * v.w;
    }
    // reduce the 4 edge-groups (lane bits 4,5)
    ax += __shfl_xor(ax, 16); ax += __shfl_xor(ax, 32);
    ay += __shfl_xor(ay, 16); ay += __shfl_xor(ay, 32);
    az += __shfl_xor(az, 16); az += __shfl_xor(az, 32);
    aw += __shfl_xor(aw, 16); aw += __shfl_xor(aw, 32);
    if (g == 0) {
        float d = dis[wid];
        float d2 = d * d;
        size_t base = ((size_t)wid << 6) + (cq << 2);
        const float4 sv = *reinterpret_cast<const float4*>(src + base);
        const float4 hv = *reinterpret_cast<const float4*>(hsrc + base);
        float4 o;
        o.x = 0.9f * (ax + d2 * sv.x) + 0.1f * hv.x;
        o.y = 0.9f * (ay + d2 * sv.y) + 0.1f * hv.y;
        o.z = 0.9f * (az + d2 * sv.z) + 0.1f * hv.z;
        o.w = 0.9f * (aw + d2 * sv.w) + 0.1f * hv.w;
        *reinterpret_cast<float4*>(dst + base) = o;
    }
}

// ---------------- log_softmax ----------------
__global__ __launch_bounds__(256) void logsm_kernel(const float* __restrict__ src,
                                                    float* __restrict__ out) {
    int wid = (blockIdx.x * 256 + threadIdx.x) >> 6;
    if (wid >= N_NODES) return;
    int lane = threadIdx.x & 63;
    float v = src[((size_t)wid << 6) + lane];
    float m = v;
#pragma unroll
    for (int s = 1; s < 64; s <<= 1) m = fmaxf(m, __shfl_xor(m, s));
    float e = __expf(v - m);
    float sum = e;
#pragma unroll
    for (int s = 1; s < 64; s <<= 1) sum += __shfl_xor(sum, s);
    out[((size_t)wid << 6) + lane] = (v - m) - __logf(sum);
}

extern "C" void kernel_launch(void* const* d_in, const int* in_sizes, int n_in,
                              void* d_out, int out_size, void* d_ws, size_t ws_size,
                              hipStream_t stream) {
    const float* x = (const float*)d_in[0];
    const int* ei = (const int*)d_in[1];
    const float* W1 = (const float*)d_in[2];
    const float* B1 = (const float*)d_in[3];
    const float* W2 = (const float*)d_in[4];
    const float* B2 = (const float*)d_in[5];
    float* out = (float*)d_out;

    const int* rows = ei;             // edge_index[0] : sources
    const int* cols = ei + N_EDGES;   // edge_index[1] : targets

    // workspace carve (104 MB total)
    char* p = (char*)d_ws;
    float* h1 = (float*)p;                     // [N,128] (also outA/outB after MLP)
    p += (size_t)N_NODES * C_HID * 4;
    float* h = (float*)p;                      // [N,64]
    p += (size_t)N_NODES * C_OUT * 4;
    int* csr_row = (int*)p;                    // [E]
    p += (size_t)N_EDGES * 4;
    float* csr_norm = (float*)p;               // [E]
    p += (size_t)N_EDGES * 4;
    int* cnt = (int*)p; p += (size_t)N_NODES * 4;
    int* offs = (int*)p; p += (size_t)(N_NODES + 1) * 4;
    int* cursor = (int*)p; p += (size_t)N_NODES * 4;
    float* dis = (float*)p; p += (size_t)N_NODES * 4;
    int* bsum = (int*)p; p += 256 * 4;

    float* outA = h1;                          // alias: first N*64 floats of h1
    float* outB = h1 + (size_t)N_NODES * C_OUT;

    hipMemsetAsync(cnt, 0, (size_t)N_NODES * 4, stream);
    hipMemsetAsync(cursor, 0, (size_t)N_NODES * 4, stream);

    const int egrid = (N_EDGES + 255) / 256;         // 12500
    const int ngrid = (N_NODES + 255) / 256;         // 391
    const int nscan = (N_NODES + 1023) / 1024;       // 98

    hist_kernel<<<egrid, 256, 0, stream>>>(cols, cnt);
    dis_kernel<<<ngrid, 256, 0, stream>>>(cnt, dis);
    scanA<<<nscan, 256, 0, stream>>>(cnt, offs, bsum, N_NODES);
    scanB<<<1, 256, 0, stream>>>(bsum, nscan);
    scanC<<<ngrid, 256, 0, stream>>>(offs, bsum, N_NODES);
    fill_kernel<<<egrid, 256, 0, stream>>>(rows, cols, dis, offs, cursor, csr_row, csr_norm);

    const int mgrid = (N_NODES + 63) / 64;           // 1563
    gemm1<<<mgrid, 256, 0, stream>>>(x, W1, B1, h1);
    gemm2<<<mgrid, 256, 0, stream>>>(h1, W2, B2, h);

    const int pgrid = N_NODES / 4;                   // 25000 (one wave per node)
    const float* src = h;
    float* dst = outA;
    for (int k = 0; k < 10; k++) {
        prop_kernel<<<pgrid, 256, 0, stream>>>(src, h, dst, offs, csr_row, csr_norm, dis);
        src = dst;
        dst = (dst == outA) ? outB : outA;
    }
    logsm_kernel<<<pgrid, 256, 0, stream>>>(src, out);
}

// Round 3
// 1727.092 us; speedup vs baseline: 1.1476x; 1.1476x over previous
//
#include <hip/hip_runtime.h>
#include <hip/hip_bf16.h>

#define N_NODES 100000
#define N_EDGES 3200000
#define C_OUT 64
#define C_HID 128
#define C_IN 512

typedef unsigned short u16;
typedef unsigned int u32;
using short8 = __attribute__((ext_vector_type(8))) short;
using f32x4 = __attribute__((ext_vector_type(4))) float;

__device__ __forceinline__ u32 f2bf(float f) {
    u32 x = __float_as_uint(f);
    return (x + 0x7fffu + ((x >> 16) & 1u)) >> 16;  // RNE
}
__device__ __forceinline__ float bf2f_lo(u32 u) { return __uint_as_float(u << 16); }
__device__ __forceinline__ float bf2f_hi(u32 u) { return __uint_as_float(u & 0xffff0000u); }

// ---------------- degree histogram ----------------
__global__ __launch_bounds__(256) void hist_kernel(const int* __restrict__ cols,
                                                   int* __restrict__ cnt) {
    int e = blockIdx.x * 256 + threadIdx.x;
    if (e < N_EDGES) atomicAdd(&cnt[cols[e]], 1);
}

__global__ __launch_bounds__(256) void dis_kernel(const int* __restrict__ cnt,
                                                  float* __restrict__ dis) {
    int i = blockIdx.x * 256 + threadIdx.x;
    if (i < N_NODES) dis[i] = rsqrtf((float)(cnt[i] + 1));  // +1 self loop
}

// ---------------- exclusive scan (3 kernels) ----------------
__global__ __launch_bounds__(256) void scanA(const int* __restrict__ cnt,
                                             int* __restrict__ offs,
                                             int* __restrict__ bsum, int n) {
    __shared__ int sh[256];
    int b = blockIdx.x, tid = threadIdx.x;
    int base = b * 1024;
    int v[4]; int s = 0;
#pragma unroll
    for (int i = 0; i < 4; i++) {
        int idx = base + tid * 4 + i;
        v[i] = (idx < n) ? cnt[idx] : 0;
        s += v[i];
    }
    sh[tid] = s;
    __syncthreads();
    for (int st = 1; st < 256; st <<= 1) {
        int a = (tid >= st) ? sh[tid - st] : 0;
        int t = sh[tid];
        __syncthreads();
        sh[tid] = t + a;
        __syncthreads();
    }
    int run = sh[tid] - s;
#pragma unroll
    for (int i = 0; i < 4; i++) {
        int idx = base + tid * 4 + i;
        run += v[i];
        if (idx < n) offs[idx + 1] = run;
    }
    if (tid == 255) bsum[b] = sh[255];
}

__global__ __launch_bounds__(256) void scanB(int* __restrict__ bsum, int nb) {
    __shared__ int sh[256];
    int tid = threadIdx.x;
    int v = (tid < nb) ? bsum[tid] : 0;
    sh[tid] = v;
    __syncthreads();
    for (int st = 1; st < 256; st <<= 1) {
        int a = (tid >= st) ? sh[tid - st] : 0;
        int t = sh[tid];
        __syncthreads();
        sh[tid] = t + a;
        __syncthreads();
    }
    if (tid < nb) bsum[tid] = sh[tid] - v;
}

__global__ __launch_bounds__(256) void scanC(int* __restrict__ offs,
                                             const int* __restrict__ bsum, int n) {
    int idx = blockIdx.x * 256 + threadIdx.x;
    if (idx < n) offs[idx + 1] += bsum[idx >> 10];
    if (idx == 0) offs[0] = 0;
}

// ---------------- CSC fill ----------------
__global__ __launch_bounds__(256) void fill_kernel(const int* __restrict__ rows,
                                                   const int* __restrict__ cols,
                                                   const float* __restrict__ dis,
                                                   const int* __restrict__ offs,
                                                   int* __restrict__ cursor,
                                                   int* __restrict__ csr_row,
                                                   float* __restrict__ csr_norm) {
    int e = blockIdx.x * 256 + threadIdx.x;
    if (e >= N_EDGES) return;
    int r = rows[e], c = cols[e];
    float w = dis[r] * dis[c];
    int p = atomicAdd(&cursor[c], 1);
    int idx = offs[c] + p;
    csr_row[idx] = r;
    csr_norm[idx] = w;
}

// ---------------- W1 transpose to bf16: W1T[128][512] ----------------
__global__ __launch_bounds__(256) void w1t_kernel(const float* __restrict__ W1,
                                                  u16* __restrict__ W1T) {
    int idx = blockIdx.x * 256 + threadIdx.x;  // 65536
    int n = idx >> 9, k = idx & 511;
    W1T[idx] = (u16)f2bf(W1[k * C_HID + n]);
}

// ---------------- GEMM1 (MFMA bf16): h1 = relu(x @ W1 + b1) ----------------
__global__ __launch_bounds__(256) void gemm1_mfma(const float* __restrict__ X,
                                                  const u16* __restrict__ W1T,
                                                  const float* __restrict__ B1,
                                                  float* __restrict__ H1) {
    __shared__ u16 xs[64][56];    // 64 rows x 32 k, padded to 56 (112B rows -> 2-way banks)
    __shared__ u16 wsT[128][56];  // 128 n x 32 k, padded
    int tid = threadIdx.x;
    int w = tid >> 6, l = tid & 63;
    int row0 = blockIdx.x * 64;

    f32x4 acc[8];
#pragma unroll
    for (int j = 0; j < 8; j++) acc[j] = (f32x4){0.f, 0.f, 0.f, 0.f};

    const int sr = tid >> 2;            // X stage: row 0..63
    const int skq = (tid & 3) * 8;      // k offset 0,8,16,24
    const int wn = tid >> 1;            // W stage: n 0..127
    const int wkh = (tid & 1) * 16;     // k offset 0 or 16

    for (int kb = 0; kb < C_IN; kb += 32) {
        // stage X tile (fp32 -> bf16)
        {
            int gr = row0 + sr;
            float4 v0 = {0, 0, 0, 0}, v1 = {0, 0, 0, 0};
            if (gr < N_NODES) {
                const float4* px =
                    reinterpret_cast<const float4*>(X + (size_t)gr * C_IN + kb + skq);
                v0 = px[0];
                v1 = px[1];
            }
            uint4 pk;
            pk.x = f2bf(v0.x) | (f2bf(v0.y) << 16);
            pk.y = f2bf(v0.z) | (f2bf(v0.w) << 16);
            pk.z = f2bf(v1.x) | (f2bf(v1.y) << 16);
            pk.w = f2bf(v1.z) | (f2bf(v1.w) << 16);
            *reinterpret_cast<uint4*>(&xs[sr][skq]) = pk;
        }
        // stage W1T tile (already bf16)
        {
            const uint4* pw =
                reinterpret_cast<const uint4*>(W1T + (size_t)wn * C_IN + kb + wkh);
            *reinterpret_cast<uint4*>(&wsT[wn][wkh]) = pw[0];
            *reinterpret_cast<uint4*>(&wsT[wn][wkh + 8]) = pw[1];
        }
        __syncthreads();
        int ar = w * 16 + (l & 15);
        int koff = (l >> 4) * 8;
        short8 a = *reinterpret_cast<const short8*>(&xs[ar][koff]);
#pragma unroll
        for (int j = 0; j < 8; j++) {
            short8 b = *reinterpret_cast<const short8*>(&wsT[j * 16 + (l & 15)][koff]);
            acc[j] = __builtin_amdgcn_mfma_f32_16x16x32_bf16(a, b, acc[j], 0, 0, 0);
        }
        __syncthreads();
    }
    // epilogue: C row=(l>>4)*4+reg, col=l&15 per 16x16 tile
    int col_lo = l & 15;
    int rbase = row0 + w * 16 + (l >> 4) * 4;
#pragma unroll
    for (int j = 0; j < 8; j++) {
        int col = j * 16 + col_lo;
        float bias = B1[col];
#pragma unroll
        for (int rr = 0; rr < 4; rr++) {
            int grow = rbase + rr;
            if (grow < N_NODES) {
                float v = acc[j][rr] + bias;
                H1[(size_t)grow * C_HID + col] = v > 0.f ? v : 0.f;
            }
        }
    }
}

// ---------------- GEMM2: h = h1 @ W2 + b2, [N,64] (fp32) ----------------
__global__ __launch_bounds__(256) void gemm2(const float* __restrict__ H1,
                                             const float* __restrict__ W2,
                                             const float* __restrict__ B2,
                                             float* __restrict__ H) {
    __shared__ float hs[64][132];
    __shared__ float ws[128][64];
    int tid = threadIdx.x;
    int tx = tid & 15, ty = tid >> 4;
    int row0 = blockIdx.x * 64;
#pragma unroll
    for (int l = 0; l < 8; l++) {
        int idx = tid + l * 256;
        int k = idx >> 4;
        int c4 = idx & 15;
        *reinterpret_cast<float4*>(&ws[k][c4 * 4]) =
            *reinterpret_cast<const float4*>(W2 + (size_t)k * C_OUT + c4 * 4);
    }
#pragma unroll
    for (int l = 0; l < 8; l++) {
        int idx = tid + l * 256;
        int r = idx >> 5;
        int k4 = idx & 31;
        int gr = row0 + r;
        float4 v = {0, 0, 0, 0};
        if (gr < N_NODES)
            v = *reinterpret_cast<const float4*>(H1 + (size_t)gr * C_HID + k4 * 4);
        hs[r][k4 * 4 + 0] = v.x;
        hs[r][k4 * 4 + 1] = v.y;
        hs[r][k4 * 4 + 2] = v.z;
        hs[r][k4 * 4 + 3] = v.w;
    }
    __syncthreads();
    float acc[4][4];
#pragma unroll
    for (int i = 0; i < 4; i++)
#pragma unroll
        for (int j = 0; j < 4; j++) acc[i][j] = 0.f;
#pragma unroll 4
    for (int k = 0; k < C_HID; k++) {
        float hv[4], wv[4];
#pragma unroll
        for (int i = 0; i < 4; i++) hv[i] = hs[ty * 4 + i][k];
#pragma unroll
        for (int j = 0; j < 4; j++) wv[j] = ws[k][tx * 4 + j];
#pragma unroll
        for (int i = 0; i < 4; i++)
#pragma unroll
            for (int j = 0; j < 4; j++) acc[i][j] += hv[i] * wv[j];
    }
#pragma unroll
    for (int i = 0; i < 4; i++) {
        int gr = row0 + ty * 4 + i;
        if (gr < N_NODES) {
#pragma unroll
            for (int j = 0; j < 4; j++) {
                int c = tx * 4 + j;
                H[(size_t)gr * C_OUT + c] = acc[i][j] + B2[c];
            }
        }
    }
}

// ---------------- h (fp32) -> hb (bf16) ----------------
__global__ __launch_bounds__(256) void conv_bf16(const float* __restrict__ h,
                                                 u16* __restrict__ hb) {
    int idx = blockIdx.x * 256 + threadIdx.x;  // one per 4 elems
    if (idx < N_NODES * 16) {
        float4 v = reinterpret_cast<const float4*>(h)[idx];
        uint2 o;
        o.x = f2bf(v.x) | (f2bf(v.y) << 16);
        o.y = f2bf(v.z) | (f2bf(v.w) << 16);
        reinterpret_cast<uint2*>(hb)[idx] = o;
    }
}

// ---------------- APPNP propagate step (bf16 state) ----------------
// one wave per node; 4 edge-groups x 16 lanes; each lane handles 4 channels (8B bf16)
__global__ __launch_bounds__(256) void prop_bf16(const u16* __restrict__ src,
                                                 const float* __restrict__ hsrc,
                                                 u16* __restrict__ dst,
                                                 const int* __restrict__ offs,
                                                 const int* __restrict__ csr_row,
                                                 const float* __restrict__ csr_norm,
                                                 const float* __restrict__ dis) {
    int wid = (blockIdx.x * 256 + threadIdx.x) >> 6;
    if (wid >= N_NODES) return;
    int lane = threadIdx.x & 63;
    int g = lane >> 4;
    int cq = lane & 15;
    int beg = offs[wid], end = offs[wid + 1];
    float a0 = 0.f, a1 = 0.f, a2 = 0.f, a3 = 0.f;
    for (int j = beg; j < end; j += 4) {
        int jj = j + g;
        int r = 0;
        float w = 0.f;
        if (jj < end) {
            r = csr_row[jj];
            w = csr_norm[jj];
        }
        uint2 v = *reinterpret_cast<const uint2*>(src + ((size_t)r << 6) + (cq << 2));
        a0 += w * bf2f_lo(v.x);
        a1 += w * bf2f_hi(v.x);
        a2 += w * bf2f_lo(v.y);
        a3 += w * bf2f_hi(v.y);
    }
    a0 += __shfl_xor(a0, 16); a0 += __shfl_xor(a0, 32);
    a1 += __shfl_xor(a1, 16); a1 += __shfl_xor(a1, 32);
    a2 += __shfl_xor(a2, 16); a2 += __shfl_xor(a2, 32);
    a3 += __shfl_xor(a3, 16); a3 += __shfl_xor(a3, 32);
    if (g == 0) {
        float d = dis[wid];
        float d2 = d * d;
        size_t base = ((size_t)wid << 6) + (cq << 2);
        uint2 sv = *reinterpret_cast<const uint2*>(src + base);
        const float4 hv = *reinterpret_cast<const float4*>(hsrc + base);
        float o0 = 0.9f * (a0 + d2 * bf2f_lo(sv.x)) + 0.1f * hv.x;
        float o1 = 0.9f * (a1 + d2 * bf2f_hi(sv.x)) + 0.1f * hv.y;
        float o2 = 0.9f * (a2 + d2 * bf2f_lo(sv.y)) + 0.1f * hv.z;
        float o3 = 0.9f * (a3 + d2 * bf2f_hi(sv.y)) + 0.1f * hv.w;
        uint2 ov;
        ov.x = f2bf(o0) | (f2bf(o1) << 16);
        ov.y = f2bf(o2) | (f2bf(o3) << 16);
        *reinterpret_cast<uint2*>(dst + base) = ov;
    }
}

// ---------------- log_softmax (bf16 in, fp32 out) ----------------
__global__ __launch_bounds__(256) void logsm_kernel(const u16* __restrict__ src,
                                                    float* __restrict__ out) {
    int wid = (blockIdx.x * 256 + threadIdx.x) >> 6;
    if (wid >= N_NODES) return;
    int lane = threadIdx.x & 63;
    float v = __uint_as_float(((u32)src[((size_t)wid << 6) + lane]) << 16);
    float m = v;
#pragma unroll
    for (int s = 1; s < 64; s <<= 1) m = fmaxf(m, __shfl_xor(m, s));
    float e = __expf(v - m);
    float sum = e;
#pragma unroll
    for (int s = 1; s < 64; s <<= 1) sum += __shfl_xor(sum, s);
    out[((size_t)wid << 6) + lane] = (v - m) - __logf(sum);
}

extern "C" void kernel_launch(void* const* d_in, const int* in_sizes, int n_in,
                              void* d_out, int out_size, void* d_ws, size_t ws_size,
                              hipStream_t stream) {
    const float* x = (const float*)d_in[0];
    const int* ei = (const int*)d_in[1];
    const float* W1 = (const float*)d_in[2];
    const float* B1 = (const float*)d_in[3];
    const float* W2 = (const float*)d_in[4];
    const float* B2 = (const float*)d_in[5];
    float* out = (float*)d_out;

    const int* rows = ei;
    const int* cols = ei + N_EDGES;

    // workspace carve (~104 MB)
    char* p = (char*)d_ws;
    float* h1 = (float*)p;                 // [N,128] fp32; reused for bf16 state bufs
    p += (size_t)N_NODES * C_HID * 4;
    float* h = (float*)p;                  // [N,64] fp32 (teleport term)
    p += (size_t)N_NODES * C_OUT * 4;
    int* csr_row = (int*)p;  p += (size_t)N_EDGES * 4;
    float* csr_norm = (float*)p; p += (size_t)N_EDGES * 4;
    int* cnt = (int*)p;      p += (size_t)N_NODES * 4;
    int* offs = (int*)p;     p += (size_t)(N_NODES + 1) * 4;
    int* cursor = (int*)p;   p += (size_t)N_NODES * 4;
    float* dis = (float*)p;  p += (size_t)N_NODES * 4;
    int* bsum = (int*)p;     p += 256 * 4;

    // W1T overlaps cursor region (cursor dead after fill; 400KB >= 128KB)
    u16* W1T = (u16*)cursor;

    // bf16 state buffers alias h1 (dead after gemm2/conv): 3 x 12.8MB in 51.2MB
    u16* hb = (u16*)h1;
    u16* stA = hb + (size_t)N_NODES * C_OUT;
    u16* stB = stA + (size_t)N_NODES * C_OUT;

    hipMemsetAsync(cnt, 0, (size_t)N_NODES * 4, stream);
    hipMemsetAsync(cursor, 0, (size_t)N_NODES * 4, stream);

    const int egrid = (N_EDGES + 255) / 256;
    const int ngrid = (N_NODES + 255) / 256;
    const int nscan = (N_NODES + 1023) / 1024;

    hist_kernel<<<egrid, 256, 0, stream>>>(cols, cnt);
    dis_kernel<<<ngrid, 256, 0, stream>>>(cnt, dis);
    scanA<<<nscan, 256, 0, stream>>>(cnt, offs, bsum, N_NODES);
    scanB<<<1, 256, 0, stream>>>(bsum, nscan);
    scanC<<<ngrid, 256, 0, stream>>>(offs, bsum, N_NODES);
    fill_kernel<<<egrid, 256, 0, stream>>>(rows, cols, dis, offs, cursor, csr_row, csr_norm);

    w1t_kernel<<<256, 256, 0, stream>>>(W1, W1T);  // after fill (aliases cursor)

    const int mgrid = (N_NODES + 63) / 64;
    gemm1_mfma<<<mgrid, 256, 0, stream>>>(x, W1T, B1, h1 /* H1 */);
    // NOTE: H1 written by gemm1_mfma must not alias hb yet -- h1 IS hb's region,
    // but hb is only written by conv_bf16 AFTER gemm2 consumed h1. Order is safe:
    // gemm1 writes h1, gemm2 reads h1 -> writes h, conv reads h -> writes hb (over h1).
    gemm2<<<mgrid, 256, 0, stream>>>(h1, W2, B2, h);
    conv_bf16<<<(N_NODES * 16 + 255) / 256, 256, 0, stream>>>(h, hb);

    const int pgrid = N_NODES / 4;  // one wave per node
    const u16* src = hb;
    u16* dst = stA;
    for (int k = 0; k < 10; k++) {
        prop_bf16<<<pgrid, 256, 0, stream>>>(src, h, dst, offs, csr_row, csr_norm, dis);
        src = dst;
        dst = (dst == stA) ? stB : stA;
    }
    logsm_kernel<<<pgrid, 256, 0, stream>>>(src, out);
}

// Round 4
// 1387.568 us; speedup vs baseline: 1.4284x; 1.2447x over previous
//
#include <hip/hip_runtime.h>
#include <hip/hip_bf16.h>

#define N_NODES 100000
#define N_EDGES 3200000
#define C_OUT 64
#define C_HID 128
#define C_IN 512

typedef unsigned short u16;
typedef unsigned int u32;
typedef long long ll;
using short8 = __attribute__((ext_vector_type(8))) short;
using f32x4 = __attribute__((ext_vector_type(4))) float;

__device__ __forceinline__ u32 f2bf(float f) {
    u32 x = __float_as_uint(f);
    return (x + 0x7fffu + ((x >> 16) & 1u)) >> 16;  // RNE
}
__device__ __forceinline__ float bf2f_lo(u32 u) { return __uint_as_float(u << 16); }
__device__ __forceinline__ float bf2f_hi(u32 u) { return __uint_as_float(u & 0xffff0000u); }

// ---------------- degree histogram ----------------
__global__ __launch_bounds__(256) void hist_kernel(const int* __restrict__ cols,
                                                   int* __restrict__ cnt) {
    int e = blockIdx.x * 256 + threadIdx.x;
    if (e < N_EDGES) atomicAdd(&cnt[__builtin_nontemporal_load(cols + e)], 1);
}

__global__ __launch_bounds__(256) void dis_kernel(const int* __restrict__ cnt,
                                                  float* __restrict__ dis) {
    int i = blockIdx.x * 256 + threadIdx.x;
    if (i < N_NODES) dis[i] = rsqrtf((float)(cnt[i] + 1));  // +1 self loop
}

// ---------------- exclusive scan (3 kernels) ----------------
__global__ __launch_bounds__(256) void scanA(const int* __restrict__ cnt,
                                             int* __restrict__ offs,
                                             int* __restrict__ bsum, int n) {
    __shared__ int sh[256];
    int b = blockIdx.x, tid = threadIdx.x;
    int base = b * 1024;
    int v[4]; int s = 0;
#pragma unroll
    for (int i = 0; i < 4; i++) {
        int idx = base + tid * 4 + i;
        v[i] = (idx < n) ? cnt[idx] : 0;
        s += v[i];
    }
    sh[tid] = s;
    __syncthreads();
    for (int st = 1; st < 256; st <<= 1) {
        int a = (tid >= st) ? sh[tid - st] : 0;
        int t = sh[tid];
        __syncthreads();
        sh[tid] = t + a;
        __syncthreads();
    }
    int run = sh[tid] - s;
#pragma unroll
    for (int i = 0; i < 4; i++) {
        int idx = base + tid * 4 + i;
        run += v[i];
        if (idx < n) offs[idx + 1] = run;
    }
    if (tid == 255) bsum[b] = sh[255];
}

__global__ __launch_bounds__(256) void scanB(int* __restrict__ bsum, int nb) {
    __shared__ int sh[256];
    int tid = threadIdx.x;
    int v = (tid < nb) ? bsum[tid] : 0;
    sh[tid] = v;
    __syncthreads();
    for (int st = 1; st < 256; st <<= 1) {
        int a = (tid >= st) ? sh[tid - st] : 0;
        int t = sh[tid];
        __syncthreads();
        sh[tid] = t + a;
        __syncthreads();
    }
    if (tid < nb) bsum[tid] = sh[tid] - v;
}

__global__ __launch_bounds__(256) void scanC(int* __restrict__ offs,
                                             const int* __restrict__ bsum, int n) {
    int idx = blockIdx.x * 256 + threadIdx.x;
    if (idx < n) offs[idx + 1] += bsum[idx >> 10];
    if (idx == 0) offs[0] = 0;
}

// ---------------- CSC fill (packed int2: row, norm) ----------------
__global__ __launch_bounds__(256) void fill_kernel(const int* __restrict__ rows,
                                                   const int* __restrict__ cols,
                                                   const float* __restrict__ dis,
                                                   const int* __restrict__ offs,
                                                   int* __restrict__ cursor,
                                                   int2* __restrict__ csr) {
    int e = blockIdx.x * 256 + threadIdx.x;
    if (e >= N_EDGES) return;
    int r = __builtin_nontemporal_load(rows + e);
    int c = __builtin_nontemporal_load(cols + e);
    float w = dis[r] * dis[c];
    int p = atomicAdd(&cursor[c], 1);
    int2 val;
    val.x = r;
    val.y = __float_as_int(w);
    csr[offs[c] + p] = val;
}

// ---------------- W1 transpose to bf16: W1T[128][512] ----------------
__global__ __launch_bounds__(256) void w1t_kernel(const float* __restrict__ W1,
                                                  u16* __restrict__ W1T) {
    int idx = blockIdx.x * 256 + threadIdx.x;  // 65536
    int n = idx >> 9, k = idx & 511;
    W1T[idx] = (u16)f2bf(W1[k * C_HID + n]);
}

// ---------------- GEMM1 (MFMA bf16): h1 = relu(x @ W1 + b1) ----------------
__global__ __launch_bounds__(256) void gemm1_mfma(const float* __restrict__ X,
                                                  const u16* __restrict__ W1T,
                                                  const float* __restrict__ B1,
                                                  float* __restrict__ H1) {
    __shared__ u16 xs[64][56];    // 64 rows x 32 k, padded to 56
    __shared__ u16 wsT[128][56];  // 128 n x 32 k, padded
    int tid = threadIdx.x;
    int w = tid >> 6, l = tid & 63;
    int row0 = blockIdx.x * 64;

    f32x4 acc[8];
#pragma unroll
    for (int j = 0; j < 8; j++) acc[j] = (f32x4){0.f, 0.f, 0.f, 0.f};

    const int sr = tid >> 2;
    const int skq = (tid & 3) * 8;
    const int wn = tid >> 1;
    const int wkh = (tid & 1) * 16;

    for (int kb = 0; kb < C_IN; kb += 32) {
        {
            int gr = row0 + sr;
            float4 v0 = {0, 0, 0, 0}, v1 = {0, 0, 0, 0};
            if (gr < N_NODES) {
                const float4* px =
                    reinterpret_cast<const float4*>(X + (size_t)gr * C_IN + kb + skq);
                v0 = px[0];
                v1 = px[1];
            }
            uint4 pk;
            pk.x = f2bf(v0.x) | (f2bf(v0.y) << 16);
            pk.y = f2bf(v0.z) | (f2bf(v0.w) << 16);
            pk.z = f2bf(v1.x) | (f2bf(v1.y) << 16);
            pk.w = f2bf(v1.z) | (f2bf(v1.w) << 16);
            *reinterpret_cast<uint4*>(&xs[sr][skq]) = pk;
        }
        {
            const uint4* pw =
                reinterpret_cast<const uint4*>(W1T + (size_t)wn * C_IN + kb + wkh);
            *reinterpret_cast<uint4*>(&wsT[wn][wkh]) = pw[0];
            *reinterpret_cast<uint4*>(&wsT[wn][wkh + 8]) = pw[1];
        }
        __syncthreads();
        int ar = w * 16 + (l & 15);
        int koff = (l >> 4) * 8;
        short8 a = *reinterpret_cast<const short8*>(&xs[ar][koff]);
#pragma unroll
        for (int j = 0; j < 8; j++) {
            short8 b = *reinterpret_cast<const short8*>(&wsT[j * 16 + (l & 15)][koff]);
            acc[j] = __builtin_amdgcn_mfma_f32_16x16x32_bf16(a, b, acc[j], 0, 0, 0);
        }
        __syncthreads();
    }
    int col_lo = l & 15;
    int rbase = row0 + w * 16 + (l >> 4) * 4;
#pragma unroll
    for (int j = 0; j < 8; j++) {
        int col = j * 16 + col_lo;
        float bias = B1[col];
#pragma unroll
        for (int rr = 0; rr < 4; rr++) {
            int grow = rbase + rr;
            if (grow < N_NODES) {
                float v = acc[j][rr] + bias;
                H1[(size_t)grow * C_HID + col] = v > 0.f ? v : 0.f;
            }
        }
    }
}

// ---------------- GEMM2: h = h1 @ W2 + b2, [N,64] (fp32) ----------------
__global__ __launch_bounds__(256) void gemm2(const float* __restrict__ H1,
                                             const float* __restrict__ W2,
                                             const float* __restrict__ B2,
                                             float* __restrict__ H) {
    __shared__ float hs[64][132];
    __shared__ float ws[128][64];
    int tid = threadIdx.x;
    int tx = tid & 15, ty = tid >> 4;
    int row0 = blockIdx.x * 64;
#pragma unroll
    for (int l = 0; l < 8; l++) {
        int idx = tid + l * 256;
        int k = idx >> 4;
        int c4 = idx & 15;
        *reinterpret_cast<float4*>(&ws[k][c4 * 4]) =
            *reinterpret_cast<const float4*>(W2 + (size_t)k * C_OUT + c4 * 4);
    }
#pragma unroll
    for (int l = 0; l < 8; l++) {
        int idx = tid + l * 256;
        int r = idx >> 5;
        int k4 = idx & 31;
        int gr = row0 + r;
        float4 v = {0, 0, 0, 0};
        if (gr < N_NODES)
            v = *reinterpret_cast<const float4*>(H1 + (size_t)gr * C_HID + k4 * 4);
        hs[r][k4 * 4 + 0] = v.x;
        hs[r][k4 * 4 + 1] = v.y;
        hs[r][k4 * 4 + 2] = v.z;
        hs[r][k4 * 4 + 3] = v.w;
    }
    __syncthreads();
    float acc[4][4];
#pragma unroll
    for (int i = 0; i < 4; i++)
#pragma unroll
        for (int j = 0; j < 4; j++) acc[i][j] = 0.f;
#pragma unroll 4
    for (int k = 0; k < C_HID; k++) {
        float hv[4], wv[4];
#pragma unroll
        for (int i = 0; i < 4; i++) hv[i] = hs[ty * 4 + i][k];
#pragma unroll
        for (int j = 0; j < 4; j++) wv[j] = ws[k][tx * 4 + j];
#pragma unroll
        for (int i = 0; i < 4; i++)
#pragma unroll
            for (int j = 0; j < 4; j++) acc[i][j] += hv[i] * wv[j];
    }
#pragma unroll
    for (int i = 0; i < 4; i++) {
        int gr = row0 + ty * 4 + i;
        if (gr < N_NODES) {
#pragma unroll
            for (int j = 0; j < 4; j++) {
                int c = tx * 4 + j;
                H[(size_t)gr * C_OUT + c] = acc[i][j] + B2[c];
            }
        }
    }
}

// ---------------- h (fp32) -> hb (bf16) ----------------
__global__ __launch_bounds__(256) void conv_bf16(const float* __restrict__ h,
                                                 u16* __restrict__ hb) {
    int idx = blockIdx.x * 256 + threadIdx.x;
    if (idx < N_NODES * 16) {
        float4 v = reinterpret_cast<const float4*>(h)[idx];
        uint2 o;
        o.x = f2bf(v.x) | (f2bf(v.y) << 16);
        o.y = f2bf(v.z) | (f2bf(v.w) << 16);
        reinterpret_cast<uint2*>(hb)[idx] = o;
    }
}

// ---------------- APPNP propagate step (bf16 state) ----------------
// one wave per node; 8 edge-groups x 8 lanes; each lane handles 8 channels (16B);
// 2-deep unroll -> 16 gathers in flight per wave iteration
__global__ __launch_bounds__(256) void prop_bf16(const u16* __restrict__ src,
                                                 const float* __restrict__ hsrc,
                                                 u16* __restrict__ dst,
                                                 const int* __restrict__ offs,
                                                 const ll* __restrict__ csr,
                                                 const float* __restrict__ dis) {
    int wid = (blockIdx.x * 256 + threadIdx.x) >> 6;
    if (wid >= N_NODES) return;
    int lane = threadIdx.x & 63;
    int g = lane >> 3;   // edge group 0..7
    int c8 = lane & 7;   // channel octet: channels c8*8 .. c8*8+7
    int beg = offs[wid], end = offs[wid + 1];
    float a0 = 0.f, a1 = 0.f, a2 = 0.f, a3 = 0.f;
    float a4 = 0.f, a5 = 0.f, a6 = 0.f, a7 = 0.f;
    const size_t coff = (size_t)(c8 << 3);
    for (int j = beg; j < end; j += 16) {
        int jj0 = j + g, jj1 = j + 8 + g;
        ll e0 = 0, e1 = 0;
        if (jj0 < end) e0 = __builtin_nontemporal_load(csr + jj0);
        if (jj1 < end) e1 = __builtin_nontemporal_load(csr + jj1);
        int r0 = (int)e0;
        float w0 = __int_as_float((int)(e0 >> 32));
        int r1 = (int)e1;
        float w1 = __int_as_float((int)(e1 >> 32));
        uint4 v0 = *reinterpret_cast<const uint4*>(src + (((size_t)r0) << 6) + coff);
        uint4 v1 = *reinterpret_cast<const uint4*>(src + (((size_t)r1) << 6) + coff);
        a0 += w0 * bf2f_lo(v0.x); a1 += w0 * bf2f_hi(v0.x);
        a2 += w0 * bf2f_lo(v0.y); a3 += w0 * bf2f_hi(v0.y);
        a4 += w0 * bf2f_lo(v0.z); a5 += w0 * bf2f_hi(v0.z);
        a6 += w0 * bf2f_lo(v0.w); a7 += w0 * bf2f_hi(v0.w);
        a0 += w1 * bf2f_lo(v1.x); a1 += w1 * bf2f_hi(v1.x);
        a2 += w1 * bf2f_lo(v1.y); a3 += w1 * bf2f_hi(v1.y);
        a4 += w1 * bf2f_lo(v1.z); a5 += w1 * bf2f_hi(v1.z);
        a6 += w1 * bf2f_lo(v1.w); a7 += w1 * bf2f_hi(v1.w);
    }
    // reduce across the 8 edge groups (lane bits 3,4,5)
    a0 += __shfl_xor(a0, 8); a0 += __shfl_xor(a0, 16); a0 += __shfl_xor(a0, 32);
    a1 += __shfl_xor(a1, 8); a1 += __shfl_xor(a1, 16); a1 += __shfl_xor(a1, 32);
    a2 += __shfl_xor(a2, 8); a2 += __shfl_xor(a2, 16); a2 += __shfl_xor(a2, 32);
    a3 += __shfl_xor(a3, 8); a3 += __shfl_xor(a3, 16); a3 += __shfl_xor(a3, 32);
    a4 += __shfl_xor(a4, 8); a4 += __shfl_xor(a4, 16); a4 += __shfl_xor(a4, 32);
    a5 += __shfl_xor(a5, 8); a5 += __shfl_xor(a5, 16); a5 += __shfl_xor(a5, 32);
    a6 += __shfl_xor(a6, 8); a6 += __shfl_xor(a6, 16); a6 += __shfl_xor(a6, 32);
    a7 += __shfl_xor(a7, 8); a7 += __shfl_xor(a7, 16); a7 += __shfl_xor(a7, 32);
    if (g == 0) {
        float d = dis[wid];
        float d2 = d * d;
        size_t base = ((size_t)wid << 6) + coff;
        uint4 sv = *reinterpret_cast<const uint4*>(src + base);
        const float4* hp = reinterpret_cast<const float4*>(hsrc + base);
        float4 h0 = hp[0], h1v = hp[1];
        float o0 = 0.9f * (a0 + d2 * bf2f_lo(sv.x)) + 0.1f * h0.x;
        float o1 = 0.9f * (a1 + d2 * bf2f_hi(sv.x)) + 0.1f * h0.y;
        float o2 = 0.9f * (a2 + d2 * bf2f_lo(sv.y)) + 0.1f * h0.z;
        float o3 = 0.9f * (a3 + d2 * bf2f_hi(sv.y)) + 0.1f * h0.w;
        float o4 = 0.9f * (a4 + d2 * bf2f_lo(sv.z)) + 0.1f * h1v.x;
        float o5 = 0.9f * (a5 + d2 * bf2f_hi(sv.z)) + 0.1f * h1v.y;
        float o6 = 0.9f * (a6 + d2 * bf2f_lo(sv.w)) + 0.1f * h1v.z;
        float o7 = 0.9f * (a7 + d2 * bf2f_hi(sv.w)) + 0.1f * h1v.w;
        uint4 ov;
        ov.x = f2bf(o0) | (f2bf(o1) << 16);
        ov.y = f2bf(o2) | (f2bf(o3) << 16);
        ov.z = f2bf(o4) | (f2bf(o5) << 16);
        ov.w = f2bf(o6) | (f2bf(o7) << 16);
        *reinterpret_cast<uint4*>(dst + base) = ov;
    }
}

// ---------------- log_softmax (bf16 in, fp32 out) ----------------
__global__ __launch_bounds__(256) void logsm_kernel(const u16* __restrict__ src,
                                                    float* __restrict__ out) {
    int wid = (blockIdx.x * 256 + threadIdx.x) >> 6;
    if (wid >= N_NODES) return;
    int lane = threadIdx.x & 63;
    float v = __uint_as_float(((u32)src[((size_t)wid << 6) + lane]) << 16);
    float m = v;
#pragma unroll
    for (int s = 1; s < 64; s <<= 1) m = fmaxf(m, __shfl_xor(m, s));
    float e = __expf(v - m);
    float sum = e;
#pragma unroll
    for (int s = 1; s < 64; s <<= 1) sum += __shfl_xor(sum, s);
    out[((size_t)wid << 6) + lane] = (v - m) - __logf(sum);
}

extern "C" void kernel_launch(void* const* d_in, const int* in_sizes, int n_in,
                              void* d_out, int out_size, void* d_ws, size_t ws_size,
                              hipStream_t stream) {
    const float* x = (const float*)d_in[0];
    const int* ei = (const int*)d_in[1];
    const float* W1 = (const float*)d_in[2];
    const float* B1 = (const float*)d_in[3];
    const float* W2 = (const float*)d_in[4];
    const float* B2 = (const float*)d_in[5];
    float* out = (float*)d_out;

    const int* rows = ei;
    const int* cols = ei + N_EDGES;

    // workspace carve (~104 MB)
    char* p = (char*)d_ws;
    float* h1 = (float*)p;                 // [N,128] fp32; reused for bf16 state bufs
    p += (size_t)N_NODES * C_HID * 4;
    float* h = (float*)p;                  // [N,64] fp32 (teleport term)
    p += (size_t)N_NODES * C_OUT * 4;
    int2* csr = (int2*)p; p += (size_t)N_EDGES * 8;   // packed (row, norm)
    int* cnt = (int*)p;      p += (size_t)N_NODES * 4;
    int* offs = (int*)p;     p += (size_t)(N_NODES + 1) * 4;
    int* cursor = (int*)p;   p += (size_t)N_NODES * 4;
    float* dis = (float*)p;  p += (size_t)N_NODES * 4;
    int* bsum = (int*)p;     p += 256 * 4;

    // W1T overlaps cursor region (cursor dead after fill; 400KB >= 128KB)
    u16* W1T = (u16*)cursor;

    // bf16 state buffers alias h1 (dead after gemm2/conv): 3 x 12.8MB in 51.2MB
    u16* hb = (u16*)h1;
    u16* stA = hb + (size_t)N_NODES * C_OUT;
    u16* stB = stA + (size_t)N_NODES * C_OUT;

    hipMemsetAsync(cnt, 0, (size_t)N_NODES * 4, stream);
    hipMemsetAsync(cursor, 0, (size_t)N_NODES * 4, stream);

    const int egrid = (N_EDGES + 255) / 256;
    const int ngrid = (N_NODES + 255) / 256;
    const int nscan = (N_NODES + 1023) / 1024;

    hist_kernel<<<egrid, 256, 0, stream>>>(cols, cnt);
    dis_kernel<<<ngrid, 256, 0, stream>>>(cnt, dis);
    scanA<<<nscan, 256, 0, stream>>>(cnt, offs, bsum, N_NODES);
    scanB<<<1, 256, 0, stream>>>(bsum, nscan);
    scanC<<<ngrid, 256, 0, stream>>>(offs, bsum, N_NODES);
    fill_kernel<<<egrid, 256, 0, stream>>>(rows, cols, dis, offs, cursor, csr);

    w1t_kernel<<<256, 256, 0, stream>>>(W1, W1T);  // after fill (aliases cursor)

    const int mgrid = (N_NODES + 63) / 64;
    gemm1_mfma<<<mgrid, 256, 0, stream>>>(x, W1T, B1, h1);
    gemm2<<<mgrid, 256, 0, stream>>>(h1, W2, B2, h);
    conv_bf16<<<(N_NODES * 16 + 255) / 256, 256, 0, stream>>>(h, hb);

    const int pgrid = N_NODES / 4;  // one wave per node
    const u16* src = hb;
    u16* dst = stA;
    for (int k = 0; k < 10; k++) {
        prop_bf16<<<pgrid, 256, 0, stream>>>(src, h, dst, offs, (const ll*)csr, dis);
        src = dst;
        dst = (dst == stA) ? stB : stA;
    }
    logsm_kernel<<<pgrid, 256, 0, stream>>>(src, out);
}